// Round 3
// baseline (463.146 us; speedup 1.0000x reference)
//
#include <hip/hip_runtime.h>
#include <cstdint>
#include <cstring>

// JAX PRNG variant: 1 = jax_threefry_partitionable=True (verified correct R1)
#define JAX_PARTITIONABLE 1

#define B_ 1024
#define P_ 512
#define K_ 128
#define MAXC 76
#define NSCORE 524288ull     // B*P
#define NRAND  67108864ull   // B*P*K
#define OFF_I  ((size_t)B_ * P_ * K_)          // 67108864
#define OFF_MT (OFF_I + (size_t)B_ * MAXC)     // + 77824
#define SELWS_BYTES ((size_t)B_ * 16 * 4)      // 64 KiB selmask in d_ws

typedef float f4 __attribute__((ext_vector_type(4)));

// 2-bit mask_type codes for all 1024 rows, passed by value (256 B kernarg)
struct MTPack { uint32_t w[B_ / 16]; };

// ---------------- Threefry2x32 (exact JAX schedule) ----------------
__host__ __device__ inline uint32_t rotl32(uint32_t v, int d) {
    return (v << d) | (v >> (32 - d));
}

__host__ __device__ inline void tf2x32(uint32_t k0, uint32_t k1,
                                       uint32_t x0, uint32_t x1,
                                       uint32_t& o0, uint32_t& o1) {
    uint32_t ks2 = k0 ^ k1 ^ 0x1BD11BDAu;
    x0 += k0; x1 += k1;
#define TF_R(r) { x0 += x1; x1 = rotl32(x1, (r)); x1 ^= x0; }
    TF_R(13) TF_R(15) TF_R(26) TF_R(6)
    x0 += k1;  x1 += ks2 + 1u;
    TF_R(17) TF_R(29) TF_R(16) TF_R(24)
    x0 += ks2; x1 += k0 + 2u;
    TF_R(13) TF_R(15) TF_R(26) TF_R(6)
    x0 += k0;  x1 += k1 + 3u;
    TF_R(17) TF_R(29) TF_R(16) TF_R(24)
    x0 += k1;  x1 += ks2 + 4u;
    TF_R(13) TF_R(15) TF_R(26) TF_R(6)
    x0 += ks2; x1 += k0 + 5u;
#undef TF_R
    o0 = x0; o1 = x1;
}

__host__ __device__ inline uint32_t jax_bits(uint32_t k0, uint32_t k1,
                                             uint64_t i, uint64_t n) {
#if JAX_PARTITIONABLE
    (void)n;
    uint32_t o0, o1;
    tf2x32(k0, k1, (uint32_t)(i >> 32), (uint32_t)i, o0, o1);
    return o0 ^ o1;
#else
    uint64_t half = n >> 1;
    uint32_t o0, o1;
    if (i < half) { tf2x32(k0, k1, (uint32_t)i, (uint32_t)(i + half), o0, o1); return o0; }
    tf2x32(k0, k1, (uint32_t)(i - half), (uint32_t)i, o0, o1); return o1;
#endif
}

__device__ inline float u01(uint32_t bits) {
    return __uint_as_float((bits >> 9) | 0x3F800000u) - 1.0f;
}

// ============ Kernel A: selection + I + mt; selmask -> d_ws ============
__global__ void __launch_bounds__(512)
select_kernel(const int* __restrict__ seq_len,
              float* __restrict__ I_out,
              float* __restrict__ mt_out,
              uint32_t* __restrict__ selws,
              MTPack mtp,
              uint32_t ks0, uint32_t ks1) {
    int b = blockIdx.x;
    int tid = threadIdx.x;
    __shared__ __align__(16) float sc[P_];

    int sl = seq_len[b];
    int n_valid = sl >> 3;
    int n_corr = (int)floorf(0.15f * (float)sl / 8.0f);   // f32, exactly as JAX

    // zero this row's selmask words (only this block touches them)
    if (tid < 16) selws[b * 16 + tid] = 0u;

    // block 0 emits mask_type (host-precomputed, 2 bits/row in kernarg)
    if (b == 0) {
        for (int j = tid; j < B_; j += 512)
            mt_out[j] = (float)((mtp.w[j >> 4] >> ((j & 15) * 2)) & 3u);
    }

    // pad I slots [n_corr, 76) with -1 (disjoint from rank-indexed writes)
    if (tid < MAXC && tid >= n_corr) I_out[(size_t)b * MAXC + tid] = -1.0f;

    // one score per thread; invalid patches padded with +inf
    {
        float s = __builtin_inff();
        if (tid < n_valid && n_corr > 0) {
            uint32_t bits = jax_bits(ks0, ks1, (uint64_t)b * P_ + tid, NSCORE);
            s = u01(bits);
        }
        sc[tid] = s;
    }
    __syncthreads();

    // stable-sort rank, one patch per thread, f4-vectorized LDS reads.
    // +inf padding handles the ragged tail (inf never increments rank).
    if (n_corr > 0 && tid < n_valid) {
        float sp = sc[tid];
        int rank = 0;
        const f4* sc4 = (const f4*)sc;
        int nq4 = (n_valid + 3) >> 2;
        for (int q4 = 0; q4 < nq4; q4++) {
            f4 s4 = sc4[q4];
            int qb = q4 << 2;
            rank += (s4.x < sp) || (s4.x == sp && qb + 0 < tid);
            rank += (s4.y < sp) || (s4.y == sp && qb + 1 < tid);
            rank += (s4.z < sp) || (s4.z == sp && qb + 2 < tid);
            rank += (s4.w < sp) || (s4.w == sp && qb + 3 < tid);
        }
        if (rank < n_corr) {
            I_out[(size_t)b * MAXC + rank] = (float)tid;
            atomicOr(&selws[b * 16 + (tid >> 5)], 1u << (tid & 31));
        }
    }
}

// ============ Kernel B: pure barrier-light stream (copy + blend) ============
// 2048 blocks x 256 threads; block hb owns a contiguous half-row (8192 f4 =
// 128 KB). Stages its 8 selmask words into LDS once, then streams with zero
// serial dependencies. Structurally a copy kernel -> should run at copy rate.
template <int T0>
__global__ void __launch_bounds__(256, (T0 == 1 ? 4 : 8))
stream_kernel(const float* __restrict__ x,
              const float* __restrict__ pos,
              const float* __restrict__ wm,
              float* __restrict__ out,
              const uint32_t* __restrict__ selws,
              uint32_t kr0, uint32_t kr1) {
    int hb = blockIdx.x;
    int tid = threadIdx.x;
    size_t base = (size_t)hb * 8192;            // f4 units
    const f4* x4 = (const f4*)x + base;
    f4*       o4 = (f4*)out + base;

    if (T0 == 2) {
        // replacement == x : pure copy
        for (int it = 0; it < 32; it += 8) {
            f4 v[8];
#pragma unroll
            for (int u = 0; u < 8; u++)
                v[u] = __builtin_nontemporal_load(&x4[tid + (it + u) * 256]);
#pragma unroll
            for (int u = 0; u < 8; u++)
                __builtin_nontemporal_store(v[u], &o4[tid + (it + u) * 256]);
        }
        return;
    }

    int row   = hb >> 1;
    int phalf = (hb & 1) * 256;                 // patch offset within row
    __shared__ uint32_t sm[8];
    if (tid < 8) sm[tid] = selws[row * 16 + (hb & 1) * 8 + tid];
    __syncthreads();

    const f4* p4  = (const f4*)pos;             // reused -> cached
    const int kq  = tid & 31;                   // float4 within patch
    f4 wmv;
    if (T0 == 0) wmv = ((const f4*)wm)[kq];

    for (int it = 0; it < 32; it += 4) {
        f4 v[4];
#pragma unroll
        for (int u = 0; u < 4; u++)
            v[u] = __builtin_nontemporal_load(&x4[tid + (it + u) * 256]);
#pragma unroll
        for (int u = 0; u < 4; u++) {
            int il = tid + (it + u) * 256;      // local f4 idx in half-row
            int pl = il >> 5;                   // local patch 0..255
            bool sel = (sm[pl >> 5] >> (pl & 31)) & 1u;
            if (sel) {
                int pp = phalf + pl;            // patch within row 0..511
                f4 c = p4[pp * (K_ / 4) + kq];
                if (T0 == 0) {
                    v[u] = wmv + c;
                } else { // T0 == 1
                    uint64_t e = (base + (uint64_t)il) * 4;  // global float idx
                    v[u].x = u01(jax_bits(kr0, kr1, e + 0, NRAND)) + c.x;
                    v[u].y = u01(jax_bits(kr0, kr1, e + 1, NRAND)) + c.y;
                    v[u].z = u01(jax_bits(kr0, kr1, e + 2, NRAND)) + c.z;
                    v[u].w = u01(jax_bits(kr0, kr1, e + 3, NRAND)) + c.w;
                }
            }
        }
#pragma unroll
        for (int u = 0; u < 4; u++)
            __builtin_nontemporal_store(v[u], &o4[tid + (it + u) * 256]);
    }
}

// ============ Fallback: R2 fused kernel (used only if d_ws too small) ======
template <int T0>
__global__ void __launch_bounds__(512, (T0 == 1 ? 4 : 8))
fused_kernel(const float* __restrict__ x,
             const float* __restrict__ pos,
             const float* __restrict__ wm,
             const int* __restrict__ seq_len,
             float* __restrict__ out,
             float* __restrict__ I_out,
             float* __restrict__ mt_out,
             MTPack mtp,
             uint32_t ks0, uint32_t ks1,
             uint32_t kr0, uint32_t kr1) {
    int b = blockIdx.x;
    int tid = threadIdx.x;
    __shared__ __align__(16) float sc[P_];
    __shared__ uint32_t selmask[P_ / 32];

    int sl = seq_len[b];
    int n_valid = sl >> 3;
    int n_corr = (int)floorf(0.15f * (float)sl / 8.0f);

    if (tid < P_ / 32) selmask[tid] = 0u;
    if (b == 0) {
        for (int j = tid; j < B_; j += 512)
            mt_out[j] = (float)((mtp.w[j >> 4] >> ((j & 15) * 2)) & 3u);
    }
    if (tid < MAXC && tid >= n_corr) I_out[(size_t)b * MAXC + tid] = -1.0f;

    if (n_corr > 0) {
        {
            float s = __builtin_inff();
            if (tid < n_valid) {
                uint32_t bits = jax_bits(ks0, ks1, (uint64_t)b * P_ + tid, NSCORE);
                s = u01(bits);
            }
            sc[tid] = s;
        }
        __syncthreads();
        if (tid < n_valid) {
            float sp = sc[tid];
            int rank = 0;
            const f4* sc4 = (const f4*)sc;
            int nq4 = (n_valid + 3) >> 2;
            for (int q4 = 0; q4 < nq4; q4++) {
                f4 s4 = sc4[q4];
                int qb = q4 << 2;
                rank += (s4.x < sp) || (s4.x == sp && qb + 0 < tid);
                rank += (s4.y < sp) || (s4.y == sp && qb + 1 < tid);
                rank += (s4.z < sp) || (s4.z == sp && qb + 2 < tid);
                rank += (s4.w < sp) || (s4.w == sp && qb + 3 < tid);
            }
            if (rank < n_corr) {
                I_out[(size_t)b * MAXC + rank] = (float)tid;
                atomicOr(&selmask[tid >> 5], 1u << (tid & 31));
            }
        }
    }
    __syncthreads();

    const f4* x4  = (const f4*)x + (size_t)b * (P_ * (K_ / 4));
    f4*       o4  = (f4*)out     + (size_t)b * (P_ * (K_ / 4));
    const f4* p4  = (const f4*)pos;
    const f4* wm4 = (const f4*)wm;

    if (T0 == 2) {
        for (int k = 0; k < 32; k += 4) {
            f4 v[4];
#pragma unroll
            for (int u = 0; u < 4; u++)
                v[u] = __builtin_nontemporal_load(&x4[tid + (k + u) * 512]);
#pragma unroll
            for (int u = 0; u < 4; u++)
                __builtin_nontemporal_store(v[u], &o4[tid + (k + u) * 512]);
        }
    } else {
        const int kq = tid & 31;
        const int pb = tid >> 5;
        f4 wmv;
        if (T0 == 0) wmv = wm4[kq];
        for (int k = 0; k < 32; k += 4) {
            f4 v[4];
#pragma unroll
            for (int u = 0; u < 4; u++)
                v[u] = __builtin_nontemporal_load(&x4[tid + (k + u) * 512]);
#pragma unroll
            for (int u = 0; u < 4; u++) {
                int pp = pb + (k + u) * 16;
                bool sel = (selmask[pp >> 5] >> (pp & 31)) & 1u;
                if (sel) {
                    f4 c = p4[pp * (K_ / 4) + kq];
                    if (T0 == 0) {
                        v[u] = wmv + c;
                    } else {
                        uint64_t e = (((uint64_t)b * P_ + pp) * K_) + (uint64_t)kq * 4;
                        v[u].x = u01(jax_bits(kr0, kr1, e + 0, NRAND)) + c.x;
                        v[u].y = u01(jax_bits(kr0, kr1, e + 1, NRAND)) + c.y;
                        v[u].z = u01(jax_bits(kr0, kr1, e + 2, NRAND)) + c.z;
                        v[u].w = u01(jax_bits(kr0, kr1, e + 3, NRAND)) + c.w;
                    }
                }
            }
#pragma unroll
            for (int u = 0; u < 4; u++)
                __builtin_nontemporal_store(v[u], &o4[tid + (k + u) * 512]);
        }
    }
}

// ---------------- Host ----------------
extern "C" void kernel_launch(void* const* d_in, const int* in_sizes, int n_in,
                              void* d_out, int out_size, void* d_ws, size_t ws_size,
                              hipStream_t stream) {
    (void)in_sizes; (void)n_in; (void)out_size;
    const float* x   = (const float*)d_in[0];
    const float* pos = (const float*)d_in[1];
    const float* wm  = (const float*)d_in[2];
    const int* seq_len = (const int*)d_in[3];
    float* out = (float*)d_out;

    // Seed-only precompute: derived keys + all 1024 mask_type codes + t0.
    static bool init_done = false;
    static MTPack mtp;
    static int t0 = 0;
    static uint32_t ks0, ks1, kr0, kr1;
    if (!init_done) {
        uint32_t kp0, kp1, sub0, sub1;
#if JAX_PARTITIONABLE
        tf2x32(0u, 42u, 0u, 0u, kp0, kp1);
        tf2x32(0u, 42u, 0u, 1u, ks0, ks1);
        tf2x32(0u, 42u, 0u, 2u, kr0, kr1);
        tf2x32(kp0, kp1, 0u, 1u, sub0, sub1);   // split(kp,2)[1]
#else
        {
            uint32_t a0, b0, a1, b1, a2, b2;
            tf2x32(0u, 42u, 0u, 3u, a0, b0);
            tf2x32(0u, 42u, 1u, 4u, a1, b1);
            tf2x32(0u, 42u, 2u, 5u, a2, b2);
            kp0 = a0; kp1 = a1; ks0 = a2; ks1 = b0; kr0 = b1; kr1 = b2;
            uint32_t c0, d0, c1, d1;
            tf2x32(kp0, kp1, 0u, 2u, c0, d0);
            tf2x32(kp0, kp1, 1u, 3u, c1, d1);
            sub0 = d0; sub1 = d1;
        }
#endif
        static uint32_t skeys[B_];
        for (int i = 0; i < B_; i++)
            skeys[i] = jax_bits(sub0, sub1, (uint64_t)i, (uint64_t)B_);
        memset(&mtp, 0, sizeof(mtp));
        for (int i = 0; i < B_; i++) {
            uint32_t ki = skeys[i];
            int rank = 0;
            for (int q = 0; q < B_; q++) {
                uint32_t kq = skeys[q];
                rank += (kq < ki) || (kq == ki && q < i);
            }
            uint32_t code = rank < 819 ? 0u : (rank < 921 ? 1u : 2u);
            mtp.w[i >> 4] |= code << ((i & 15) * 2);
        }
        t0 = (int)(mtp.w[0] & 3u);
        init_done = true;
    }

    float* I_out  = out + OFF_I;
    float* mt_out = out + OFF_MT;

    bool split = (d_ws != nullptr) && (ws_size >= SELWS_BYTES);
    if (split) {
        uint32_t* selws = (uint32_t*)d_ws;
        select_kernel<<<dim3(B_), dim3(512), 0, stream>>>(
            seq_len, I_out, mt_out, selws, mtp, ks0, ks1);
        switch (t0) {
        case 0:
            stream_kernel<0><<<dim3(2 * B_), dim3(256), 0, stream>>>(
                x, pos, wm, out, selws, kr0, kr1);
            break;
        case 1:
            stream_kernel<1><<<dim3(2 * B_), dim3(256), 0, stream>>>(
                x, pos, wm, out, selws, kr0, kr1);
            break;
        default:
            stream_kernel<2><<<dim3(2 * B_), dim3(256), 0, stream>>>(
                x, pos, wm, out, selws, kr0, kr1);
            break;
        }
    } else {
        switch (t0) {
        case 0:
            fused_kernel<0><<<dim3(B_), dim3(512), 0, stream>>>(
                x, pos, wm, seq_len, out, I_out, mt_out, mtp, ks0, ks1, kr0, kr1);
            break;
        case 1:
            fused_kernel<1><<<dim3(B_), dim3(512), 0, stream>>>(
                x, pos, wm, seq_len, out, I_out, mt_out, mtp, ks0, ks1, kr0, kr1);
            break;
        default:
            fused_kernel<2><<<dim3(B_), dim3(512), 0, stream>>>(
                x, pos, wm, seq_len, out, I_out, mt_out, mtp, ks0, ks1, kr0, kr1);
            break;
        }
    }
}

// Round 4
// 455.169 us; speedup vs baseline: 1.0175x; 1.0175x over previous
//
#include <hip/hip_runtime.h>
#include <cstdint>
#include <cstring>

// JAX PRNG variant: 1 = jax_threefry_partitionable=True (verified correct R1)
#define JAX_PARTITIONABLE 1

#define B_ 1024
#define P_ 512
#define K_ 128
#define MAXC 76
#define NSCORE 524288ull     // B*P
#define NRAND  67108864ull   // B*P*K
#define OFF_I  ((size_t)B_ * P_ * K_)          // 67108864
#define OFF_MT (OFF_I + (size_t)B_ * MAXC)     // + 77824

typedef float f4 __attribute__((ext_vector_type(4)));

// 2-bit mask_type codes for all 1024 rows, passed by value (256 B kernarg)
struct MTPack { uint32_t w[B_ / 16]; };

// ---------------- Threefry2x32 (exact JAX schedule) ----------------
__host__ __device__ inline uint32_t rotl32(uint32_t v, int d) {
    return (v << d) | (v >> (32 - d));
}

__host__ __device__ inline void tf2x32(uint32_t k0, uint32_t k1,
                                       uint32_t x0, uint32_t x1,
                                       uint32_t& o0, uint32_t& o1) {
    uint32_t ks2 = k0 ^ k1 ^ 0x1BD11BDAu;
    x0 += k0; x1 += k1;
#define TF_R(r) { x0 += x1; x1 = rotl32(x1, (r)); x1 ^= x0; }
    TF_R(13) TF_R(15) TF_R(26) TF_R(6)
    x0 += k1;  x1 += ks2 + 1u;
    TF_R(17) TF_R(29) TF_R(16) TF_R(24)
    x0 += ks2; x1 += k0 + 2u;
    TF_R(13) TF_R(15) TF_R(26) TF_R(6)
    x0 += k0;  x1 += k1 + 3u;
    TF_R(17) TF_R(29) TF_R(16) TF_R(24)
    x0 += k1;  x1 += ks2 + 4u;
    TF_R(13) TF_R(15) TF_R(26) TF_R(6)
    x0 += ks2; x1 += k0 + 5u;
#undef TF_R
    o0 = x0; o1 = x1;
}

__host__ __device__ inline uint32_t jax_bits(uint32_t k0, uint32_t k1,
                                             uint64_t i, uint64_t n) {
#if JAX_PARTITIONABLE
    (void)n;
    uint32_t o0, o1;
    tf2x32(k0, k1, (uint32_t)(i >> 32), (uint32_t)i, o0, o1);
    return o0 ^ o1;
#else
    uint64_t half = n >> 1;
    uint32_t o0, o1;
    if (i < half) { tf2x32(k0, k1, (uint32_t)i, (uint32_t)(i + half), o0, o1); return o0; }
    tf2x32(k0, k1, (uint32_t)(i - half), (uint32_t)i, o0, o1); return o1;
#endif
}

__device__ inline float u01(uint32_t bits) {
    return __uint_as_float((bits >> 9) | 0x3F800000u) - 1.0f;
}

// ---------------- Single fused kernel: selection + I + mt + x_out ----------
// T0 = mask_type[0] (compile-time specialized; host picks the instantiation).
// Single dispatch is mandatory: R0->R1 and R2->R3 measured ~15-20 us fixed
// cost per extra graph dispatch node.
// Loads are PLAIN (m13's 6.29 TB/s copy used plain float4; NT-load hint
// suspected of limiting read throughput). Stores stay NT (268 MB >> L2).
// First 4 f4/thread are prefetched BEFORE the selection prologue so the
// memory pipe is busy during the rank computation.
template <int T0>
__global__ void __launch_bounds__(512, (T0 == 1 ? 4 : 8))
fused_kernel(const float* __restrict__ x,
             const float* __restrict__ pos,
             const float* __restrict__ wm,
             const int* __restrict__ seq_len,
             float* __restrict__ out,
             float* __restrict__ I_out,
             float* __restrict__ mt_out,
             MTPack mtp,
             uint32_t ks0, uint32_t ks1,
             uint32_t kr0, uint32_t kr1) {
    int b = blockIdx.x;
    int tid = threadIdx.x;
    __shared__ __align__(16) float sc[P_];
    __shared__ uint32_t selmask[P_ / 32];

    const f4* x4  = (const f4*)x + (size_t)b * (P_ * (K_ / 4));
    f4*       o4  = (f4*)out     + (size_t)b * (P_ * (K_ / 4));

    // ---- prefetch group 0 (4 f4/thread) -- in flight during the prologue
    f4 pre0 = x4[tid];
    f4 pre1 = x4[tid + 512];
    f4 pre2 = x4[tid + 1024];
    f4 pre3 = x4[tid + 1536];

    int sl = seq_len[b];
    int n_valid = sl >> 3;
    int n_corr = (int)floorf(0.15f * (float)sl / 8.0f);   // f32, exactly as JAX

    if (tid < P_ / 32) selmask[tid] = 0u;

    // block 0 also emits mask_type (host-precomputed, 2 bits/row in kernarg)
    if (b == 0) {
        for (int j = tid; j < B_; j += 512)
            mt_out[j] = (float)((mtp.w[j >> 4] >> ((j & 15) * 2)) & 3u);
    }

    // pad I slots [n_corr, 76) with -1 (disjoint from rank-indexed writes)
    if (tid < MAXC && tid >= n_corr) I_out[(size_t)b * MAXC + tid] = -1.0f;

    if (n_corr > 0) {   // block-uniform branch (legal around __syncthreads)
        // one score per thread; invalid patches padded with +inf
        {
            float s = __builtin_inff();
            if (tid < n_valid) {
                uint32_t bits = jax_bits(ks0, ks1, (uint64_t)b * P_ + tid, NSCORE);
                s = u01(bits);
            }
            sc[tid] = s;
        }
        __syncthreads();

        // stable-sort rank, one patch per thread, f4-vectorized LDS reads.
        // +inf padding handles the ragged tail (inf never increments rank).
        if (tid < n_valid) {
            float sp = sc[tid];
            int rank = 0;
            const f4* sc4 = (const f4*)sc;
            int nq4 = (n_valid + 3) >> 2;
            for (int q4 = 0; q4 < nq4; q4++) {
                f4 s4 = sc4[q4];
                int qb = q4 << 2;
                rank += (s4.x < sp) || (s4.x == sp && qb + 0 < tid);
                rank += (s4.y < sp) || (s4.y == sp && qb + 1 < tid);
                rank += (s4.z < sp) || (s4.z == sp && qb + 2 < tid);
                rank += (s4.w < sp) || (s4.w == sp && qb + 3 < tid);
            }
            if (rank < n_corr) {
                I_out[(size_t)b * MAXC + rank] = (float)tid;
                atomicOr(&selmask[tid >> 5], 1u << (tid & 31));
            }
        }
    }
    __syncthreads();

    // ---- stream the row: 16384 float4, 32/thread, unroll x4 ----
    const f4* p4  = (const f4*)pos;                    // reused 1024x -> cached
    const f4* wm4 = (const f4*)wm;

    if (T0 == 2) {
        // replacement == x : pure copy
        __builtin_nontemporal_store(pre0, &o4[tid]);
        __builtin_nontemporal_store(pre1, &o4[tid + 512]);
        __builtin_nontemporal_store(pre2, &o4[tid + 1024]);
        __builtin_nontemporal_store(pre3, &o4[tid + 1536]);
        for (int k = 4; k < 32; k += 4) {
            f4 v[4];
#pragma unroll
            for (int u = 0; u < 4; u++)
                v[u] = x4[tid + (k + u) * 512];
#pragma unroll
            for (int u = 0; u < 4; u++)
                __builtin_nontemporal_store(v[u], &o4[tid + (k + u) * 512]);
        }
    } else {
        const int kq = tid & 31;    // float4 within patch (constant per lane)
        const int pb = tid >> 5;    // base patch (0..15)
        f4 wmv;
        if (T0 == 0) wmv = wm4[kq];

        // blend helper: group g (0..31), value v -> output value
        auto blend = [&](f4 v, int g) -> f4 {
            int pp = pb + g * 16;
            bool sel = (selmask[pp >> 5] >> (pp & 31)) & 1u;
            if (sel) {
                f4 c = p4[pp * (K_ / 4) + kq];
                if (T0 == 0) {
                    v = wmv + c;
                } else { // T0 == 1
                    uint64_t e = (((uint64_t)b * P_ + pp) * K_) + (uint64_t)kq * 4;
                    v.x = u01(jax_bits(kr0, kr1, e + 0, NRAND)) + c.x;
                    v.y = u01(jax_bits(kr0, kr1, e + 1, NRAND)) + c.y;
                    v.z = u01(jax_bits(kr0, kr1, e + 2, NRAND)) + c.z;
                    v.w = u01(jax_bits(kr0, kr1, e + 3, NRAND)) + c.w;
                }
            }
            return v;
        };

        __builtin_nontemporal_store(blend(pre0, 0), &o4[tid]);
        __builtin_nontemporal_store(blend(pre1, 1), &o4[tid + 512]);
        __builtin_nontemporal_store(blend(pre2, 2), &o4[tid + 1024]);
        __builtin_nontemporal_store(blend(pre3, 3), &o4[tid + 1536]);

        for (int k = 4; k < 32; k += 4) {
            f4 v[4];
#pragma unroll
            for (int u = 0; u < 4; u++)
                v[u] = x4[tid + (k + u) * 512];
#pragma unroll
            for (int u = 0; u < 4; u++)
                v[u] = blend(v[u], k + u);
#pragma unroll
            for (int u = 0; u < 4; u++)
                __builtin_nontemporal_store(v[u], &o4[tid + (k + u) * 512]);
        }
    }
}

// ---------------- Host ----------------
extern "C" void kernel_launch(void* const* d_in, const int* in_sizes, int n_in,
                              void* d_out, int out_size, void* d_ws, size_t ws_size,
                              hipStream_t stream) {
    (void)in_sizes; (void)n_in; (void)d_ws; (void)ws_size; (void)out_size;
    const float* x   = (const float*)d_in[0];
    const float* pos = (const float*)d_in[1];
    const float* wm  = (const float*)d_in[2];
    const int* seq_len = (const int*)d_in[3];
    float* out = (float*)d_out;

    // Seed-only precompute: derived keys + all 1024 mask_type codes + t0.
    static bool init_done = false;
    static MTPack mtp;
    static int t0 = 0;
    static uint32_t ks0, ks1, kr0, kr1;
    if (!init_done) {
        uint32_t kp0, kp1, sub0, sub1;
#if JAX_PARTITIONABLE
        tf2x32(0u, 42u, 0u, 0u, kp0, kp1);
        tf2x32(0u, 42u, 0u, 1u, ks0, ks1);
        tf2x32(0u, 42u, 0u, 2u, kr0, kr1);
        tf2x32(kp0, kp1, 0u, 1u, sub0, sub1);   // split(kp,2)[1]
#else
        {
            uint32_t a0, b0, a1, b1, a2, b2;
            tf2x32(0u, 42u, 0u, 3u, a0, b0);
            tf2x32(0u, 42u, 1u, 4u, a1, b1);
            tf2x32(0u, 42u, 2u, 5u, a2, b2);
            kp0 = a0; kp1 = a1; ks0 = a2; ks1 = b0; kr0 = b1; kr1 = b2;
            uint32_t c0, d0, c1, d1;
            tf2x32(kp0, kp1, 0u, 2u, c0, d0);
            tf2x32(kp0, kp1, 1u, 3u, c1, d1);
            sub0 = d0; sub1 = d1;
        }
#endif
        static uint32_t skeys[B_];
        for (int i = 0; i < B_; i++)
            skeys[i] = jax_bits(sub0, sub1, (uint64_t)i, (uint64_t)B_);
        memset(&mtp, 0, sizeof(mtp));
        for (int i = 0; i < B_; i++) {
            uint32_t ki = skeys[i];
            int rank = 0;
            for (int q = 0; q < B_; q++) {
                uint32_t kq = skeys[q];
                rank += (kq < ki) || (kq == ki && q < i);
            }
            uint32_t code = rank < 819 ? 0u : (rank < 921 ? 1u : 2u);
            mtp.w[i >> 4] |= code << ((i & 15) * 2);
        }
        t0 = (int)(mtp.w[0] & 3u);
        init_done = true;
    }

    float* I_out  = out + OFF_I;
    float* mt_out = out + OFF_MT;

    switch (t0) {
    case 0:
        fused_kernel<0><<<dim3(B_), dim3(512), 0, stream>>>(
            x, pos, wm, seq_len, out, I_out, mt_out, mtp, ks0, ks1, kr0, kr1);
        break;
    case 1:
        fused_kernel<1><<<dim3(B_), dim3(512), 0, stream>>>(
            x, pos, wm, seq_len, out, I_out, mt_out, mtp, ks0, ks1, kr0, kr1);
        break;
    default:
        fused_kernel<2><<<dim3(B_), dim3(512), 0, stream>>>(
            x, pos, wm, seq_len, out, I_out, mt_out, mtp, ks0, ks1, kr0, kr1);
        break;
    }
}

// Round 5
// 444.867 us; speedup vs baseline: 1.0411x; 1.0232x over previous
//
#include <hip/hip_runtime.h>
#include <cstdint>
#include <cstring>

// JAX PRNG variant: 1 = jax_threefry_partitionable=True (verified correct R1)
#define JAX_PARTITIONABLE 1

#define B_ 1024
#define P_ 512
#define K_ 128
#define MAXC 76
#define NSCORE 524288ull     // B*P
#define NRAND  67108864ull   // B*P*K
#define OFF_I  ((size_t)B_ * P_ * K_)          // 67108864
#define OFF_MT (OFF_I + (size_t)B_ * MAXC)     // + 77824

typedef float f4 __attribute__((ext_vector_type(4)));

// 2-bit mask_type codes for all 1024 rows, passed by value (256 B kernarg)
struct MTPack { uint32_t w[B_ / 16]; };

// ---------------- Threefry2x32 (exact JAX schedule) ----------------
__host__ __device__ inline uint32_t rotl32(uint32_t v, int d) {
    return (v << d) | (v >> (32 - d));
}

__host__ __device__ inline void tf2x32(uint32_t k0, uint32_t k1,
                                       uint32_t x0, uint32_t x1,
                                       uint32_t& o0, uint32_t& o1) {
    uint32_t ks2 = k0 ^ k1 ^ 0x1BD11BDAu;
    x0 += k0; x1 += k1;
#define TF_R(r) { x0 += x1; x1 = rotl32(x1, (r)); x1 ^= x0; }
    TF_R(13) TF_R(15) TF_R(26) TF_R(6)
    x0 += k1;  x1 += ks2 + 1u;
    TF_R(17) TF_R(29) TF_R(16) TF_R(24)
    x0 += ks2; x1 += k0 + 2u;
    TF_R(13) TF_R(15) TF_R(26) TF_R(6)
    x0 += k0;  x1 += k1 + 3u;
    TF_R(17) TF_R(29) TF_R(16) TF_R(24)
    x0 += k1;  x1 += ks2 + 4u;
    TF_R(13) TF_R(15) TF_R(26) TF_R(6)
    x0 += ks2; x1 += k0 + 5u;
#undef TF_R
    o0 = x0; o1 = x1;
}

__host__ __device__ inline uint32_t jax_bits(uint32_t k0, uint32_t k1,
                                             uint64_t i, uint64_t n) {
#if JAX_PARTITIONABLE
    (void)n;
    uint32_t o0, o1;
    tf2x32(k0, k1, (uint32_t)(i >> 32), (uint32_t)i, o0, o1);
    return o0 ^ o1;
#else
    uint64_t half = n >> 1;
    uint32_t o0, o1;
    if (i < half) { tf2x32(k0, k1, (uint32_t)i, (uint32_t)(i + half), o0, o1); return o0; }
    tf2x32(k0, k1, (uint32_t)(i - half), (uint32_t)i, o0, o1); return o1;
#endif
}

__device__ inline float u01(uint32_t bits) {
    return __uint_as_float((bits >> 9) | 0x3F800000u) - 1.0f;
}

// ---------------- Single fused kernel: selection + I + mt + x_out ----------
// T0 = mask_type[0] (compile-time specialized; host picks the instantiation).
// Single dispatch is mandatory: R0->R1 and R2->R3 measured ~15-20 us fixed
// cost per extra graph dispatch node.
// R4 counters: NT-store version ran 163 us @ 2.47 TB/s HBM (31% peak),
// VALU 8% -- store path suspected (harness fill does 6.5 TB/s with plain
// stores on the same buffer). R5: PLAIN stores everywhere; this is the only
// change vs R4 (clean A/B on store policy).
template <int T0>
__global__ void __launch_bounds__(512, (T0 == 1 ? 4 : 8))
fused_kernel(const float* __restrict__ x,
             const float* __restrict__ pos,
             const float* __restrict__ wm,
             const int* __restrict__ seq_len,
             float* __restrict__ out,
             float* __restrict__ I_out,
             float* __restrict__ mt_out,
             MTPack mtp,
             uint32_t ks0, uint32_t ks1,
             uint32_t kr0, uint32_t kr1) {
    int b = blockIdx.x;
    int tid = threadIdx.x;
    __shared__ __align__(16) float sc[P_];
    __shared__ uint32_t selmask[P_ / 32];

    const f4* x4  = (const f4*)x + (size_t)b * (P_ * (K_ / 4));
    f4*       o4  = (f4*)out     + (size_t)b * (P_ * (K_ / 4));

    // ---- prefetch group 0 (4 f4/thread) -- in flight during the prologue
    f4 pre0 = x4[tid];
    f4 pre1 = x4[tid + 512];
    f4 pre2 = x4[tid + 1024];
    f4 pre3 = x4[tid + 1536];

    int sl = seq_len[b];
    int n_valid = sl >> 3;
    int n_corr = (int)floorf(0.15f * (float)sl / 8.0f);   // f32, exactly as JAX

    if (tid < P_ / 32) selmask[tid] = 0u;

    // block 0 also emits mask_type (host-precomputed, 2 bits/row in kernarg)
    if (b == 0) {
        for (int j = tid; j < B_; j += 512)
            mt_out[j] = (float)((mtp.w[j >> 4] >> ((j & 15) * 2)) & 3u);
    }

    // pad I slots [n_corr, 76) with -1 (disjoint from rank-indexed writes)
    if (tid < MAXC && tid >= n_corr) I_out[(size_t)b * MAXC + tid] = -1.0f;

    if (n_corr > 0) {   // block-uniform branch (legal around __syncthreads)
        // one score per thread; invalid patches padded with +inf
        {
            float s = __builtin_inff();
            if (tid < n_valid) {
                uint32_t bits = jax_bits(ks0, ks1, (uint64_t)b * P_ + tid, NSCORE);
                s = u01(bits);
            }
            sc[tid] = s;
        }
        __syncthreads();

        // stable-sort rank, one patch per thread, f4-vectorized LDS reads.
        // +inf padding handles the ragged tail (inf never increments rank).
        if (tid < n_valid) {
            float sp = sc[tid];
            int rank = 0;
            const f4* sc4 = (const f4*)sc;
            int nq4 = (n_valid + 3) >> 2;
            for (int q4 = 0; q4 < nq4; q4++) {
                f4 s4 = sc4[q4];
                int qb = q4 << 2;
                rank += (s4.x < sp) || (s4.x == sp && qb + 0 < tid);
                rank += (s4.y < sp) || (s4.y == sp && qb + 1 < tid);
                rank += (s4.z < sp) || (s4.z == sp && qb + 2 < tid);
                rank += (s4.w < sp) || (s4.w == sp && qb + 3 < tid);
            }
            if (rank < n_corr) {
                I_out[(size_t)b * MAXC + rank] = (float)tid;
                atomicOr(&selmask[tid >> 5], 1u << (tid & 31));
            }
        }
    }
    __syncthreads();

    // ---- stream the row: 16384 float4, 32/thread, unroll x4 ----
    const f4* p4  = (const f4*)pos;                    // reused 1024x -> cached
    const f4* wm4 = (const f4*)wm;

    if (T0 == 2) {
        // replacement == x : pure copy
        o4[tid]        = pre0;
        o4[tid + 512]  = pre1;
        o4[tid + 1024] = pre2;
        o4[tid + 1536] = pre3;
        for (int k = 4; k < 32; k += 4) {
            f4 v[4];
#pragma unroll
            for (int u = 0; u < 4; u++)
                v[u] = x4[tid + (k + u) * 512];
#pragma unroll
            for (int u = 0; u < 4; u++)
                o4[tid + (k + u) * 512] = v[u];
        }
    } else {
        const int kq = tid & 31;    // float4 within patch (constant per lane)
        const int pb = tid >> 5;    // base patch (0..15)
        f4 wmv;
        if (T0 == 0) wmv = wm4[kq];

        // blend helper: group g (0..31), value v -> output value
        auto blend = [&](f4 v, int g) -> f4 {
            int pp = pb + g * 16;
            bool sel = (selmask[pp >> 5] >> (pp & 31)) & 1u;
            if (sel) {
                f4 c = p4[pp * (K_ / 4) + kq];
                if (T0 == 0) {
                    v = wmv + c;
                } else { // T0 == 1
                    uint64_t e = (((uint64_t)b * P_ + pp) * K_) + (uint64_t)kq * 4;
                    v.x = u01(jax_bits(kr0, kr1, e + 0, NRAND)) + c.x;
                    v.y = u01(jax_bits(kr0, kr1, e + 1, NRAND)) + c.y;
                    v.z = u01(jax_bits(kr0, kr1, e + 2, NRAND)) + c.z;
                    v.w = u01(jax_bits(kr0, kr1, e + 3, NRAND)) + c.w;
                }
            }
            return v;
        };

        o4[tid]        = blend(pre0, 0);
        o4[tid + 512]  = blend(pre1, 1);
        o4[tid + 1024] = blend(pre2, 2);
        o4[tid + 1536] = blend(pre3, 3);

        for (int k = 4; k < 32; k += 4) {
            f4 v[4];
#pragma unroll
            for (int u = 0; u < 4; u++)
                v[u] = x4[tid + (k + u) * 512];
#pragma unroll
            for (int u = 0; u < 4; u++)
                v[u] = blend(v[u], k + u);
#pragma unroll
            for (int u = 0; u < 4; u++)
                o4[tid + (k + u) * 512] = v[u];
        }
    }
}

// ---------------- Host ----------------
extern "C" void kernel_launch(void* const* d_in, const int* in_sizes, int n_in,
                              void* d_out, int out_size, void* d_ws, size_t ws_size,
                              hipStream_t stream) {
    (void)in_sizes; (void)n_in; (void)d_ws; (void)ws_size; (void)out_size;
    const float* x   = (const float*)d_in[0];
    const float* pos = (const float*)d_in[1];
    const float* wm  = (const float*)d_in[2];
    const int* seq_len = (const int*)d_in[3];
    float* out = (float*)d_out;

    // Seed-only precompute: derived keys + all 1024 mask_type codes + t0.
    static bool init_done = false;
    static MTPack mtp;
    static int t0 = 0;
    static uint32_t ks0, ks1, kr0, kr1;
    if (!init_done) {
        uint32_t kp0, kp1, sub0, sub1;
#if JAX_PARTITIONABLE
        tf2x32(0u, 42u, 0u, 0u, kp0, kp1);
        tf2x32(0u, 42u, 0u, 1u, ks0, ks1);
        tf2x32(0u, 42u, 0u, 2u, kr0, kr1);
        tf2x32(kp0, kp1, 0u, 1u, sub0, sub1);   // split(kp,2)[1]
#else
        {
            uint32_t a0, b0, a1, b1, a2, b2;
            tf2x32(0u, 42u, 0u, 3u, a0, b0);
            tf2x32(0u, 42u, 1u, 4u, a1, b1);
            tf2x32(0u, 42u, 2u, 5u, a2, b2);
            kp0 = a0; kp1 = a1; ks0 = a2; ks1 = b0; kr0 = b1; kr1 = b2;
            uint32_t c0, d0, c1, d1;
            tf2x32(kp0, kp1, 0u, 2u, c0, d0);
            tf2x32(kp0, kp1, 1u, 3u, c1, d1);
            sub0 = d0; sub1 = d1;
        }
#endif
        static uint32_t skeys[B_];
        for (int i = 0; i < B_; i++)
            skeys[i] = jax_bits(sub0, sub1, (uint64_t)i, (uint64_t)B_);
        memset(&mtp, 0, sizeof(mtp));
        for (int i = 0; i < B_; i++) {
            uint32_t ki = skeys[i];
            int rank = 0;
            for (int q = 0; q < B_; q++) {
                uint32_t kq = skeys[q];
                rank += (kq < ki) || (kq == ki && q < i);
            }
            uint32_t code = rank < 819 ? 0u : (rank < 921 ? 1u : 2u);
            mtp.w[i >> 4] |= code << ((i & 15) * 2);
        }
        t0 = (int)(mtp.w[0] & 3u);
        init_done = true;
    }

    float* I_out  = out + OFF_I;
    float* mt_out = out + OFF_MT;

    switch (t0) {
    case 0:
        fused_kernel<0><<<dim3(B_), dim3(512), 0, stream>>>(
            x, pos, wm, seq_len, out, I_out, mt_out, mtp, ks0, ks1, kr0, kr1);
        break;
    case 1:
        fused_kernel<1><<<dim3(B_), dim3(512), 0, stream>>>(
            x, pos, wm, seq_len, out, I_out, mt_out, mtp, ks0, ks1, kr0, kr1);
        break;
    default:
        fused_kernel<2><<<dim3(B_), dim3(512), 0, stream>>>(
            x, pos, wm, seq_len, out, I_out, mt_out, mtp, ks0, ks1, kr0, kr1);
        break;
    }
}

// Round 7
// 441.674 us; speedup vs baseline: 1.0486x; 1.0072x over previous
//
#include <hip/hip_runtime.h>
#include <cstdint>
#include <cstring>

// JAX PRNG variant: 1 = jax_threefry_partitionable=True (verified correct R1)
#define JAX_PARTITIONABLE 1

#define B_ 1024
#define P_ 512
#define K_ 128
#define MAXC 76
#define NSCORE 524288ull     // B*P
#define NRAND  67108864ull   // B*P*K
#define OFF_I  ((size_t)B_ * P_ * K_)          // 67108864
#define OFF_MT (OFF_I + (size_t)B_ * MAXC)     // + 77824

typedef float f4 __attribute__((ext_vector_type(4)));

// 2-bit mask_type codes for all 1024 rows, passed by value (256 B kernarg)
struct MTPack { uint32_t w[B_ / 16]; };

// ---------------- Threefry2x32 (exact JAX schedule) ----------------
__host__ __device__ inline uint32_t rotl32(uint32_t v, int d) {
    return (v << d) | (v >> (32 - d));
}

__host__ __device__ inline void tf2x32(uint32_t k0, uint32_t k1,
                                       uint32_t x0, uint32_t x1,
                                       uint32_t& o0, uint32_t& o1) {
    uint32_t ks2 = k0 ^ k1 ^ 0x1BD11BDAu;
    x0 += k0; x1 += k1;
#define TF_R(r) { x0 += x1; x1 = rotl32(x1, (r)); x1 ^= x0; }
    TF_R(13) TF_R(15) TF_R(26) TF_R(6)
    x0 += k1;  x1 += ks2 + 1u;
    TF_R(17) TF_R(29) TF_R(16) TF_R(24)
    x0 += ks2; x1 += k0 + 2u;
    TF_R(13) TF_R(15) TF_R(26) TF_R(6)
    x0 += k0;  x1 += k1 + 3u;
    TF_R(17) TF_R(29) TF_R(16) TF_R(24)
    x0 += k1;  x1 += ks2 + 4u;
    TF_R(13) TF_R(15) TF_R(26) TF_R(6)
    x0 += ks2; x1 += k0 + 5u;
#undef TF_R
    o0 = x0; o1 = x1;
}

__host__ __device__ inline uint32_t jax_bits(uint32_t k0, uint32_t k1,
                                             uint64_t i, uint64_t n) {
#if JAX_PARTITIONABLE
    (void)n;
    uint32_t o0, o1;
    tf2x32(k0, k1, (uint32_t)(i >> 32), (uint32_t)i, o0, o1);
    return o0 ^ o1;
#else
    uint64_t half = n >> 1;
    uint32_t o0, o1;
    if (i < half) { tf2x32(k0, k1, (uint32_t)i, (uint32_t)(i + half), o0, o1); return o0; }
    tf2x32(k0, k1, (uint32_t)(i - half), (uint32_t)i, o0, o1); return o1;
#endif
}

__device__ inline float u01(uint32_t bits) {
    return __uint_as_float((bits >> 9) | 0x3F800000u) - 1.0f;
}

// ---------------- Single fused kernel: selection + I + mt + x_out ----------
// T0 = mask_type[0] (compile-time specialized; host picks the instantiation).
// Single dispatch mandatory (R0/R3: ~15-20 us per extra dispatch node).
// R2/R4/R5 A/Bs: cache policy (NT vs plain) is neutral (+-10 us); stream
// stuck at ~3.4 TB/s effective. Theory under test (R6 re-run; R6 bench was
// an infra failure): {load4 -> blend -> store4} with register reuse forces
// each wave to drain stores before next loads issue (vmcnt register-reuse
// hazard) -> MLP halved. Fix: 2-deep double-buffered register pipeline,
// fully unrolled with NAMED buffer variables (no runtime indexing, rule #20),
// so group g+1 loads are in flight while group g blends+stores.
template <int T0>
__global__ void __launch_bounds__(512, (T0 == 1 ? 4 : 8))
fused_kernel(const float* __restrict__ x,
             const float* __restrict__ pos,
             const float* __restrict__ wm,
             const int* __restrict__ seq_len,
             float* __restrict__ out,
             float* __restrict__ I_out,
             float* __restrict__ mt_out,
             MTPack mtp,
             uint32_t ks0, uint32_t ks1,
             uint32_t kr0, uint32_t kr1) {
    int b = blockIdx.x;
    int tid = threadIdx.x;
    __shared__ __align__(16) float sc[P_];
    __shared__ uint32_t selmask[P_ / 32];

    const f4* x4  = (const f4*)x + (size_t)b * (P_ * (K_ / 4));
    f4*       o4  = (f4*)out     + (size_t)b * (P_ * (K_ / 4));

    // ---- prefetch group 0 (4 f4/thread) -- in flight during the prologue
    f4 a0 = x4[tid];
    f4 a1 = x4[tid + 512];
    f4 a2 = x4[tid + 1024];
    f4 a3 = x4[tid + 1536];

    int sl = seq_len[b];
    int n_valid = sl >> 3;
    int n_corr = (int)floorf(0.15f * (float)sl / 8.0f);   // f32, exactly as JAX

    if (tid < P_ / 32) selmask[tid] = 0u;

    // block 0 also emits mask_type (host-precomputed, 2 bits/row in kernarg)
    if (b == 0) {
        for (int j = tid; j < B_; j += 512)
            mt_out[j] = (float)((mtp.w[j >> 4] >> ((j & 15) * 2)) & 3u);
    }

    // pad I slots [n_corr, 76) with -1 (disjoint from rank-indexed writes)
    if (tid < MAXC && tid >= n_corr) I_out[(size_t)b * MAXC + tid] = -1.0f;

    if (n_corr > 0) {   // block-uniform branch (legal around __syncthreads)
        // one score per thread; invalid patches padded with +inf
        {
            float s = __builtin_inff();
            if (tid < n_valid) {
                uint32_t bits = jax_bits(ks0, ks1, (uint64_t)b * P_ + tid, NSCORE);
                s = u01(bits);
            }
            sc[tid] = s;
        }
        __syncthreads();

        // stable-sort rank, one patch per thread, f4-vectorized LDS reads.
        // +inf padding handles the ragged tail (inf never increments rank).
        if (tid < n_valid) {
            float sp = sc[tid];
            int rank = 0;
            const f4* sc4 = (const f4*)sc;
            int nq4 = (n_valid + 3) >> 2;
            for (int q4 = 0; q4 < nq4; q4++) {
                f4 s4 = sc4[q4];
                int qb = q4 << 2;
                rank += (s4.x < sp) || (s4.x == sp && qb + 0 < tid);
                rank += (s4.y < sp) || (s4.y == sp && qb + 1 < tid);
                rank += (s4.z < sp) || (s4.z == sp && qb + 2 < tid);
                rank += (s4.w < sp) || (s4.w == sp && qb + 3 < tid);
            }
            if (rank < n_corr) {
                I_out[(size_t)b * MAXC + rank] = (float)tid;
                atomicOr(&selmask[tid >> 5], 1u << (tid & 31));
            }
        }
    }
    __syncthreads();

    // ---- stream the row: 16384 float4, 32/thread, 8 groups of 4,
    //      software-pipelined double buffer (named registers, no arrays) ----
    const f4* p4  = (const f4*)pos;                    // reused 1024x -> cached
    const f4* wm4 = (const f4*)wm;

    const int kq = tid & 31;    // float4 within patch (constant per lane)
    const int pb = tid >> 5;    // base patch (0..15)
    f4 wmv;
    if (T0 == 0) wmv = wm4[kq];

    // blend helper: group g (0..31), value v -> output value
    auto blend = [&](f4 v, int g) -> f4 {
        if (T0 == 2) return v;                 // replacement == x : pure copy
        int pp = pb + g * 16;
        bool sel = (selmask[pp >> 5] >> (pp & 31)) & 1u;
        if (sel) {
            f4 c = p4[pp * (K_ / 4) + kq];
            if (T0 == 0) {
                v = wmv + c;
            } else { // T0 == 1
                uint64_t e = (((uint64_t)b * P_ + pp) * K_) + (uint64_t)kq * 4;
                v.x = u01(jax_bits(kr0, kr1, e + 0, NRAND)) + c.x;
                v.y = u01(jax_bits(kr0, kr1, e + 1, NRAND)) + c.y;
                v.z = u01(jax_bits(kr0, kr1, e + 2, NRAND)) + c.z;
                v.w = u01(jax_bits(kr0, kr1, e + 3, NRAND)) + c.w;
            }
        }
        return v;
    };

    f4 b0, b1, b2, b3;
    // LOAD_B(g): issue group g's 4 loads into b0..b3 (no deps on a0..a3)
#define LOAD_B(g) \
    b0 = x4[tid + ((g)*4 + 0) * 512]; b1 = x4[tid + ((g)*4 + 1) * 512]; \
    b2 = x4[tid + ((g)*4 + 2) * 512]; b3 = x4[tid + ((g)*4 + 3) * 512];
#define LOAD_A(g) \
    a0 = x4[tid + ((g)*4 + 0) * 512]; a1 = x4[tid + ((g)*4 + 1) * 512]; \
    a2 = x4[tid + ((g)*4 + 2) * 512]; a3 = x4[tid + ((g)*4 + 3) * 512];
#define STORE_A(g) \
    o4[tid + ((g)*4 + 0) * 512] = blend(a0, (g)*4 + 0); \
    o4[tid + ((g)*4 + 1) * 512] = blend(a1, (g)*4 + 1); \
    o4[tid + ((g)*4 + 2) * 512] = blend(a2, (g)*4 + 2); \
    o4[tid + ((g)*4 + 3) * 512] = blend(a3, (g)*4 + 3);
#define STORE_B(g) \
    o4[tid + ((g)*4 + 0) * 512] = blend(b0, (g)*4 + 0); \
    o4[tid + ((g)*4 + 1) * 512] = blend(b1, (g)*4 + 1); \
    o4[tid + ((g)*4 + 2) * 512] = blend(b2, (g)*4 + 2); \
    o4[tid + ((g)*4 + 3) * 512] = blend(b3, (g)*4 + 3);

    // group 0 already in a0..a3 (prefetched before prologue)
    LOAD_B(1)  STORE_A(0)
    LOAD_A(2)  STORE_B(1)
    LOAD_B(3)  STORE_A(2)
    LOAD_A(4)  STORE_B(3)
    LOAD_B(5)  STORE_A(4)
    LOAD_A(6)  STORE_B(5)
    LOAD_B(7)  STORE_A(6)
               STORE_B(7)

#undef LOAD_A
#undef LOAD_B
#undef STORE_A
#undef STORE_B
}

// ---------------- Host ----------------
extern "C" void kernel_launch(void* const* d_in, const int* in_sizes, int n_in,
                              void* d_out, int out_size, void* d_ws, size_t ws_size,
                              hipStream_t stream) {
    (void)in_sizes; (void)n_in; (void)d_ws; (void)ws_size; (void)out_size;
    const float* x   = (const float*)d_in[0];
    const float* pos = (const float*)d_in[1];
    const float* wm  = (const float*)d_in[2];
    const int* seq_len = (const int*)d_in[3];
    float* out = (float*)d_out;

    // Seed-only precompute: derived keys + all 1024 mask_type codes + t0.
    static bool init_done = false;
    static MTPack mtp;
    static int t0 = 0;
    static uint32_t ks0, ks1, kr0, kr1;
    if (!init_done) {
        uint32_t kp0, kp1, sub0, sub1;
#if JAX_PARTITIONABLE
        tf2x32(0u, 42u, 0u, 0u, kp0, kp1);
        tf2x32(0u, 42u, 0u, 1u, ks0, ks1);
        tf2x32(0u, 42u, 0u, 2u, kr0, kr1);
        tf2x32(kp0, kp1, 0u, 1u, sub0, sub1);   // split(kp,2)[1]
#else
        {
            uint32_t a0, b0, a1, b1, a2, b2;
            tf2x32(0u, 42u, 0u, 3u, a0, b0);
            tf2x32(0u, 42u, 1u, 4u, a1, b1);
            tf2x32(0u, 42u, 2u, 5u, a2, b2);
            kp0 = a0; kp1 = a1; ks0 = a2; ks1 = b0; kr0 = b1; kr1 = b2;
            uint32_t c0, d0, c1, d1;
            tf2x32(kp0, kp1, 0u, 2u, c0, d0);
            tf2x32(kp0, kp1, 1u, 3u, c1, d1);
            sub0 = d0; sub1 = d1;
        }
#endif
        static uint32_t skeys[B_];
        for (int i = 0; i < B_; i++)
            skeys[i] = jax_bits(sub0, sub1, (uint64_t)i, (uint64_t)B_);
        memset(&mtp, 0, sizeof(mtp));
        for (int i = 0; i < B_; i++) {
            uint32_t ki = skeys[i];
            int rank = 0;
            for (int q = 0; q < B_; q++) {
                uint32_t kq = skeys[q];
                rank += (kq < ki) || (kq == ki && q < i);
            }
            uint32_t code = rank < 819 ? 0u : (rank < 921 ? 1u : 2u);
            mtp.w[i >> 4] |= code << ((i & 15) * 2);
        }
        t0 = (int)(mtp.w[0] & 3u);
        init_done = true;
    }

    float* I_out  = out + OFF_I;
    float* mt_out = out + OFF_MT;

    switch (t0) {
    case 0:
        fused_kernel<0><<<dim3(B_), dim3(512), 0, stream>>>(
            x, pos, wm, seq_len, out, I_out, mt_out, mtp, ks0, ks1, kr0, kr1);
        break;
    case 1:
        fused_kernel<1><<<dim3(B_), dim3(512), 0, stream>>>(
            x, pos, wm, seq_len, out, I_out, mt_out, mtp, ks0, ks1, kr0, kr1);
        break;
    default:
        fused_kernel<2><<<dim3(B_), dim3(512), 0, stream>>>(
            x, pos, wm, seq_len, out, I_out, mt_out, mtp, ks0, ks1, kr0, kr1);
        break;
    }
}